// Round 1
// 3850.291 us; speedup vs baseline: 1.2900x; 1.2900x over previous
//
#include <hip/hip_runtime.h>
#include <hip/hip_fp16.h>

// WFDSA: wavelet dual-branch cosine attention. B=2048, N=256, C=96, H=3, d=32.
// Workspace layout (303.1 MB total):
//   qn  : half [B][H][N][32]   = 100663296 B   (l2-normalized q)
//   knl : float[B][H][64][32]  =  50331648 B   (normalized low keys)
//   vl  : float[B][H][64][32]  =  50331648 B
//   knh : float[B][H][64][32]  =  50331648 B
//   vh  : float[B][H][64][32]  =  50331648 B
//   W2  : float[96][192]       =     73728 B   (proj_w @ fuse_lh_w folded)
//   b2  : float[96]            =       384 B
//   WtH : half [9][96][288]    =    497664 B   (conv weights repacked, hi)
//   WtL : half [9][96][288]    =    497664 B   (conv weights repacked, lo residual)

#define B_ 2048
#define N_ 256
#define C_ 96
#define H_ 3
#define D_ 32

typedef __half half_t;
typedef __attribute__((ext_vector_type(8))) _Float16 f16x8;
typedef __attribute__((ext_vector_type(4))) float f32x4;

// ---------------- K0: W2 = proj_w @ fuse_lh_w ; b2 = proj_w @ fuse_b + proj_b
__global__ __launch_bounds__(192) void wfdsa_k0(
    const float* __restrict__ proj_w, const float* __restrict__ proj_b,
    const float* __restrict__ fuse_w, const float* __restrict__ fuse_b,
    float* __restrict__ W2, float* __restrict__ b2)
{
  int c = blockIdx.x;      // 96 blocks
  int j = threadIdx.x;     // 192 threads
  float acc = 0.f;
  for (int m = 0; m < 96; ++m)
    acc = fmaf(proj_w[c*96 + m], fuse_w[m*192 + j], acc);
  W2[c*192 + j] = acc;
  if (j == 0) {
    float a2 = proj_b[c];
    for (int m = 0; m < 96; ++m) a2 = fmaf(proj_w[c*96 + m], fuse_b[m], a2);
    b2[c] = a2;
  }
}

// ---------------- K0b: repack conv_w [96][288][3][3] f32 -> Wt[t][96][288] half hi/lo
__global__ __launch_bounds__(256) void wfdsa_k0b(
    const float* __restrict__ convw, half_t* __restrict__ WtH, half_t* __restrict__ WtL)
{
  int idx = blockIdx.x*256 + threadIdx.x;       // 9*96*288 = 248832 exactly
  if (idx >= 9*96*288) return;
  int ci = idx % 288; int rest = idx / 288; int co = rest % 96; int t = rest / 96;
  float w = convw[((size_t)co*288 + ci)*9 + t];
  half_t hi = __float2half(w);
  WtH[idx] = hi;
  WtL[idx] = __float2half(w - __half2float(hi));
}

// ---------------- K1: q = x @ q_w^T + q_b, per-head l2 norm -> qn (half)
__global__ __launch_bounds__(256) void wfdsa_k1(
    const float* __restrict__ x, const float* __restrict__ qw,
    const float* __restrict__ qb, half_t* __restrict__ qn)
{
  __shared__ float xs[64*97];   // stride 97: conflict-free per-lane rows
  __shared__ float qs[64*97];
  __shared__ float nrm[192];
  const int tid = threadIdx.x;
  const int b = blockIdx.x;
  const int r0 = blockIdx.y * 64;
  const int lane = tid & 63;
  const int wv = __builtin_amdgcn_readfirstlane(tid >> 6);

  const float* xsrc = x + ((size_t)b*N_ + r0)*C_;
  for (int idx = tid; idx < 64*96; idx += 256)
    xs[(idx/96)*97 + (idx%96)] = xsrc[idx];
  __syncthreads();

  float acc[24];
  #pragma unroll
  for (int u = 0; u < 24; ++u) acc[u] = qb[wv*24 + u];
  for (int i = 0; i < 96; ++i) {
    float xv = xs[lane*97 + i];
    #pragma unroll
    for (int u = 0; u < 24; ++u)
      acc[u] = fmaf(xv, qw[(wv*24 + u)*96 + i], acc[u]);  // uniform -> s_load
  }
  #pragma unroll
  for (int u = 0; u < 24; ++u) qs[lane*97 + wv*24 + u] = acc[u];
  __syncthreads();

  if (tid < 192) {                 // 64 rows x 3 heads
    int r = tid/3, h = tid - 3*(tid/3);
    float ss = 0.f;
    #pragma unroll
    for (int dd = 0; dd < 32; ++dd) {
      float v = qs[r*97 + h*32 + dd];
      ss = fmaf(v, v, ss);
    }
    nrm[tid] = 1.f / fmaxf(sqrtf(ss), 1e-12f);
  }
  __syncthreads();

  for (int idx = tid; idx < 64*96; idx += 256) {
    int r = idx/96, o = idx%96;
    int h = o >> 5, dd = o & 31;
    qn[(((size_t)b*H_ + h)*N_ + r0 + r)*D_ + dd] =
        __float2half(qs[r*97 + o] * nrm[r*3 + h]);
  }
}

// ---------------- K2: per-batch NLWT -> kv_low ; 3x3 conv via f16 MFMA -> kv_high
// One block per batch, 4 waves. LDS 50.8 KB -> 3 blocks/CU.
//   [0, 38480)      highs_T: half [65 rows][296 halves], row stride 592 B (16-aligned).
//                   row = position (64) + zero sentinel row 64; col = sub*96 + c.
//                   After conv: xh_s float[96][65] aliases [0, 24960).
//   [38480, 50768)  A_s: half [96][64]  (approx subband, c-major, for kv_low)
__global__ __launch_bounds__(256, 3) void wfdsa_k2(
    const float* __restrict__ x,
    const float* __restrict__ kvlw, const float* __restrict__ kvlb,
    const float* __restrict__ kvhw, const float* __restrict__ kvhb,
    const half_t* __restrict__ WtH, const half_t* __restrict__ WtL,
    const float* __restrict__ convb,
    float* __restrict__ knl, float* __restrict__ vl,
    float* __restrict__ knh, float* __restrict__ vh)
{
  __shared__ __align__(16) char smem[50768];
  half_t* hT   = (half_t*)smem;               // row r at byte r*592
  float*  xh_s = (float*)smem;                // [96][65] (aliases hT after conv)
  half_t* A_s  = (half_t*)(smem + 38480);     // [96][64]

  const int tid = threadIdx.x;
  const int b = blockIdx.x;
  const int lane = tid & 63;
  const int wv = __builtin_amdgcn_readfirstlane(tid >> 6);
  const int yy = lane >> 3, xx = lane & 7;

  // zero sentinel row 64 of highs_T (conv SAME-padding reads land here)
  if (tid < 148) ((unsigned*)(smem + 64*592))[tid] = 0u;

  // ---- Phase 1: NLWT. Wave-local: rolls via shuffles, NO barriers inside.
  // Wave wv owns channels [wv*24, wv*24+24), 2 per iter via float2 loads.
  {
    const float* xb = x + (size_t)b*N_*C_;
    const int n00 = yy*32 + xx*2;                       // (2y)*16 + 2x
    const int sl1 = (lane + 8) & 63;                    // (y+1, x)
    const int sl2 = (lane & 56) | ((xx + 1) & 7);       // (y, x+1)
    const int sl3 = (sl1 & 56) | ((xx + 1) & 7);        // (y+1, x+1)
    for (int i = 0; i < 24; i += 2) {
      const int c = wv*24 + i;
      const float2 v00 = *(const float2*)(xb + (size_t)n00*96 + c);
      const float2 v01 = *(const float2*)(xb + (size_t)(n00+1)*96 + c);
      const float2 v10 = *(const float2*)(xb + (size_t)(n00+16)*96 + c);
      const float2 v11 = *(const float2*)(xb + (size_t)(n00+17)*96 + c);
      #pragma unroll
      for (int j = 0; j < 2; ++j) {
        const float x00 = j ? v00.y : v00.x;
        const float x01 = j ? v01.y : v01.x;
        const float x10 = j ? v10.y : v10.x;
        const float x11 = j ? v11.y : v11.x;
        // t = U1 @ [x00,x01,x10,x11]
        float t0 =  0.8664f*x00 + 0.1026f*x01 + 0.4852f*x10 - 0.0574f*x11;
        float t1 = -0.1026f*x00 + 0.8664f*x01 - 0.0574f*x10 - 0.4852f*x11;
        float t2 =  0.4852f*x00 + 0.0574f*x01 - 0.8664f*x10 + 0.1026f*x11;
        float t3 =  0.0574f*x00 - 0.4852f*x01 - 0.1026f*x10 - 0.8664f*x11;
        // rolls: pure lane permutations within the wave
        float a0 = t0;
        float a1 = __shfl(t1, sl1, 64);
        float a2 = __shfl(t2, sl2, 64);
        float a3 = __shfl(t3, sl3, 64);
        // subbands = U2 @ a
        float sA =  1.3968f*a0 + 0.2212f*a1 - 0.2212f*a2 - 1.3968f*a3;
        float sB = -0.2212f*a0 + 1.3968f*a1 - 1.3968f*a2 + 0.2212f*a3;
        float sC = -0.5412f*a0 - 1.3066f*a1 - 1.3066f*a2 - 0.5412f*a3;
        float sD =  1.3066f*a0 - 0.5412f*a1 - 0.5412f*a2 + 1.3066f*a3;
        A_s[(c+j)*64 + lane] = __float2half(sA);
        half_t* hrow = hT + lane*296;         // position-major for MFMA B-frags
        hrow[c+j]        = __float2half(sB);
        hrow[96 + c+j]   = __float2half(sC);
        hrow[192 + c+j]  = __float2half(sD);
      }
    }
  }
  __syncthreads();   // A_s + highs_T visible

  // ---- Phase 2: kv_low (wave = head, lane = position); wave 3 skips ahead to conv
  if (wv < 3) {
    const int h = wv, pos = lane;
    float accK[32], accV[32];
    #pragma unroll
    for (int dd = 0; dd < 32; ++dd) {
      accK[dd] = kvlb[h*32 + dd];
      accV[dd] = kvlb[96 + h*32 + dd];
    }
    for (int c = 0; c < 96; ++c) {
      float av = __half2float(A_s[c*64 + pos]);
      const float* wk  = kvlw + (size_t)(h*32)*96 + c;       // uniform rows -> s_load
      const float* wvp = kvlw + (size_t)(96 + h*32)*96 + c;
      #pragma unroll
      for (int dd = 0; dd < 32; ++dd) {
        accK[dd] = fmaf(av, wk[(size_t)dd*96], accK[dd]);
        accV[dd] = fmaf(av, wvp[(size_t)dd*96], accV[dd]);
      }
    }
    float ss = 0.f;
    #pragma unroll
    for (int dd = 0; dd < 32; ++dd) ss = fmaf(accK[dd], accK[dd], ss);
    float sc = 1.f / fmaxf(sqrtf(ss), 1e-12f);
    float* ko = knl + (((size_t)b*H_ + h)*64 + pos)*D_;
    float* vo = vl  + (((size_t)b*H_ + h)*64 + pos)*D_;
    #pragma unroll
    for (int dd = 0; dd < 32; ++dd) { ko[dd] = accK[dd]*sc; vo[dd] = accV[dd]; }
  }

  // ---- Phase 3: 3x3 SAME conv (288->96) via MFMA f16, hi/lo-split weights.
  // out = sum_t Wt[96x288] @ B_t[288x64]; B_t = row-shifted highs_T (zero row 64).
  // Wave wv owns positions [wv*16, wv*16+16) (B cols); 6 m-tiles of 16 out-chans.
  f32x4 acc[6];
  {
    #pragma unroll
    for (int m = 0; m < 6; ++m) acc[m] = (f32x4){0.f, 0.f, 0.f, 0.f};
    const int col = lane & 15;          // A row index == B col index
    const int kb  = lane >> 4;          // K-block (8 halves)
    const int pos = wv*16 + col;
    const int py = pos >> 3, px = pos & 7;
    const half_t* ah0 = WtH + (size_t)col*288 + kb*8;
    const half_t* al0 = WtL + (size_t)col*288 + kb*8;
    #pragma unroll 1
    for (int t = 0; t < 9; ++t) {
      const int ny = py + t/3 - 1, nx = px + t%3 - 1;
      const int srow = (((unsigned)ny < 8u) && ((unsigned)nx < 8u)) ? ny*8 + nx : 64;
      const char* bb = smem + srow*592 + kb*16;
      const size_t tb = (size_t)t*96*288;
      for (int kk = 0; kk < 9; ++kk) {
        const f16x8 bf = *(const f16x8*)(bb + kk*64);
        #pragma unroll
        for (int m = 0; m < 6; ++m) {
          const f16x8 ah = *(const f16x8*)(ah0 + tb + (size_t)m*4608 + kk*32);
          const f16x8 al = *(const f16x8*)(al0 + tb + (size_t)m*4608 + kk*32);
          acc[m] = __builtin_amdgcn_mfma_f32_16x16x32_f16(ah, bf, acc[m], 0, 0, 0);
          acc[m] = __builtin_amdgcn_mfma_f32_16x16x32_f16(al, bf, acc[m], 0, 0, 0);
        }
      }
    }
  }
  __syncthreads();   // all conv reads of highs_T done -> region becomes xh_s

  // epilogue: bias + LeakyReLU(0.2) -> xh_s. C/D layout: col=lane&15, row=(lane>>4)*4+reg
  {
    const int col = lane & 15, kb = lane >> 4;
    const int pos = wv*16 + col;
    #pragma unroll
    for (int m = 0; m < 6; ++m) {
      #pragma unroll
      for (int r = 0; r < 4; ++r) {
        const int co = m*16 + kb*4 + r;
        float v = acc[m][r] + convb[co];
        xh_s[co*65 + pos] = (v >= 0.f) ? v : 0.2f*v;
      }
    }
  }
  __syncthreads();

  // ---- Phase 4: kv_high ----
  if (wv < 3) {
    const int h = wv, pos = lane;
    float accK[32], accV[32];
    #pragma unroll
    for (int dd = 0; dd < 32; ++dd) {
      accK[dd] = kvhb[h*32 + dd];
      accV[dd] = kvhb[96 + h*32 + dd];
    }
    for (int c = 0; c < 96; ++c) {
      float av = xh_s[c*65 + pos];
      const float* wk  = kvhw + (size_t)(h*32)*96 + c;
      const float* wvp = kvhw + (size_t)(96 + h*32)*96 + c;
      #pragma unroll
      for (int dd = 0; dd < 32; ++dd) {
        accK[dd] = fmaf(av, wk[(size_t)dd*96], accK[dd]);
        accV[dd] = fmaf(av, wvp[(size_t)dd*96], accV[dd]);
      }
    }
    float ss = 0.f;
    #pragma unroll
    for (int dd = 0; dd < 32; ++dd) ss = fmaf(accK[dd], accK[dd], ss);
    float sc = 1.f / fmaxf(sqrtf(ss), 1e-12f);
    float* ko = knh + (((size_t)b*H_ + h)*64 + pos)*D_;
    float* vo = vh  + (((size_t)b*H_ + h)*64 + pos)*D_;
    #pragma unroll
    for (int dd = 0; dd < 32; ++dd) { ko[dd] = accK[dd]*sc; vo[dd] = accV[dd]; }
  }
}

// ---------------- K3: dual-branch attention + folded fuse/proj GEMM
__global__ __launch_bounds__(256) void wfdsa_k3(
    const half_t* __restrict__ qn,
    const float* __restrict__ knl, const float* __restrict__ vl,
    const float* __restrict__ knh, const float* __restrict__ vh,
    const float* __restrict__ W2, const float* __restrict__ b2,
    const float* __restrict__ lsl, const float* __restrict__ lsh,
    float* __restrict__ out)
{
  __shared__ float out_s[64*97];     // padded: lane-major conflict-free
  __shared__ float logit_s[64*65];
  __shared__ float a_s[64*33];
  const int tid = threadIdx.x;
  const int b = blockIdx.x;
  const int r0 = blockIdx.y * 64;
  const int lane = tid & 63;
  const int wv = __builtin_amdgcn_readfirstlane(tid >> 6);

  for (int idx = tid; idx < 64*96; idx += 256)
    out_s[(idx/96)*97 + (idx%96)] = b2[idx%96];

  const float LOG100 = 4.605170185988091f;
  for (int h = 0; h < 3; ++h) {
    float q[32];
    const half_t* qp = qn + (((size_t)b*H_ + h)*N_ + r0 + lane)*D_;
    #pragma unroll
    for (int dd = 0; dd < 32; ++dd) q[dd] = __half2float(qp[dd]);
    for (int br = 0; br < 2; ++br) {
      const float* kn = (br ? knh : knl) + (((size_t)b*H_ + h)*64)*D_;
      const float* vv = (br ? vh  : vl ) + (((size_t)b*H_ + h)*64)*D_;
      float sc = __expf(fminf((br ? lsh : lsl)[h], LOG100));
      __syncthreads();
      // A: logits, wave wv computes keys [wv*16, wv*16+16)
      for (int kk = 0; kk < 16; ++kk) {
        int k = wv*16 + kk;
        const float* kr = kn + k*32;         // uniform -> s_load row
        float acc = 0.f;
        #pragma unroll
        for (int dd = 0; dd < 32; ++dd) acc = fmaf(q[dd], kr[dd], acc);
        logit_s[lane*65 + k] = acc * sc;
      }
      __syncthreads();
      // B: per-row softmax stats (each wave duplicates) + PV for dd chunk wv*8..+8
      float m = -1e30f;
      for (int k = 0; k < 64; ++k) m = fmaxf(m, logit_s[lane*65 + k]);
      float s = 0.f;
      for (int k = 0; k < 64; ++k) s += __expf(logit_s[lane*65 + k] - m);
      float rs = 1.f / s;
      float o8[8];
      #pragma unroll
      for (int j = 0; j < 8; ++j) o8[j] = 0.f;
      for (int k = 0; k < 64; ++k) {
        float wgt = __expf(logit_s[lane*65 + k] - m) * rs;
        const float* vr = vv + k*32 + wv*8;  // uniform -> s_load chunk
        #pragma unroll
        for (int j = 0; j < 8; ++j) o8[j] = fmaf(wgt, vr[j], o8[j]);
      }
      #pragma unroll
      for (int j = 0; j < 8; ++j) a_s[lane*33 + wv*8 + j] = o8[j];
      __syncthreads();
      // C: out[r][c] += sum_dd a[r][dd] * W2[c][br*96 + dd*3 + h]
      float a[32];
      #pragma unroll
      for (int dd = 0; dd < 32; ++dd) a[dd] = a_s[lane*33 + dd];
      for (int u = 0; u < 24; ++u) {
        int c = wv*24 + u;
        const float* wr = W2 + (size_t)c*192 + br*96 + h;   // uniform -> s_load
        float acc = 0.f;
        #pragma unroll
        for (int dd = 0; dd < 32; ++dd) acc = fmaf(a[dd], wr[dd*3], acc);
        out_s[lane*97 + c] += acc;
      }
    }
  }
  __syncthreads();
  float* op = out + ((size_t)b*N_ + r0)*C_;
  for (int idx = tid; idx < 64*96; idx += 256)
    op[idx] = out_s[(idx/96)*97 + (idx%96)];
}

extern "C" void kernel_launch(void* const* d_in, const int* in_sizes, int n_in,
                              void* d_out, int out_size, void* d_ws, size_t ws_size,
                              hipStream_t stream)
{
  const float* x     = (const float*)d_in[0];
  const float* q_w   = (const float*)d_in[1];
  const float* q_b   = (const float*)d_in[2];
  const float* kvlw  = (const float*)d_in[3];
  const float* kvlb  = (const float*)d_in[4];
  const float* kvhw  = (const float*)d_in[5];
  const float* kvhb  = (const float*)d_in[6];
  const float* convw = (const float*)d_in[7];
  const float* convb = (const float*)d_in[8];
  const float* fusew = (const float*)d_in[9];
  const float* fuseb = (const float*)d_in[10];
  const float* projw = (const float*)d_in[11];
  const float* projb = (const float*)d_in[12];
  const float* lsl   = (const float*)d_in[13];
  const float* lsh   = (const float*)d_in[14];
  float* out = (float*)d_out;

  char* ws = (char*)d_ws;
  half_t* qn = (half_t*)ws;  ws += (size_t)B_*H_*N_*D_*sizeof(half_t);
  float* knl = (float*)ws;   ws += (size_t)B_*H_*64*D_*sizeof(float);
  float* vl  = (float*)ws;   ws += (size_t)B_*H_*64*D_*sizeof(float);
  float* knh = (float*)ws;   ws += (size_t)B_*H_*64*D_*sizeof(float);
  float* vh  = (float*)ws;   ws += (size_t)B_*H_*64*D_*sizeof(float);
  float* W2  = (float*)ws;   ws += (size_t)96*192*sizeof(float);
  float* b2  = (float*)ws;   ws += (size_t)96*sizeof(float);
  half_t* WtH = (half_t*)ws; ws += (size_t)9*96*288*sizeof(half_t);
  half_t* WtL = (half_t*)ws; ws += (size_t)9*96*288*sizeof(half_t);
  // total used: ~303.1 MB of d_ws

  wfdsa_k0<<<96, 192, 0, stream>>>(projw, projb, fusew, fuseb, W2, b2);
  wfdsa_k0b<<<972, 256, 0, stream>>>(convw, WtH, WtL);
  wfdsa_k1<<<dim3(B_, 4), 256, 0, stream>>>(x, q_w, q_b, qn);
  wfdsa_k2<<<B_, 256, 0, stream>>>(x, kvlw, kvlb, kvhw, kvhb, WtH, WtL, convb,
                                   knl, vl, knh, vh);
  wfdsa_k3<<<dim3(B_, 4), 256, 0, stream>>>(qn, knl, vl, knh, vh, W2, b2,
                                            lsl, lsh, out);
}

// Round 2
// 2128.128 us; speedup vs baseline: 2.3340x; 1.8092x over previous
//
#include <hip/hip_runtime.h>
#include <hip/hip_fp16.h>

// WFDSA: wavelet dual-branch cosine attention. B=2048, N=256, C=96, H=3, d=32.
// Workspace layout (~202.4 MB):
//   qn  : half [B][H][256][32] = 100663296 B   (l2-normalized q)
//   knl : half [B][H][64][32]  =  25165824 B   (normalized low keys)
//   vtl : half [B][H][32][64]  =  25165824 B   (low values, TRANSPOSED dd-major)
//   knh : half [B][H][64][32]  =  25165824 B
//   vth : half [B][H][32][64]  =  25165824 B
//   W2p : half [96][192]       =     36864 B   (proj@fuse folded, cols permuted to br*96+h*32+dd)
//   b2  : float[96]            =       384 B
//   WtH : half [9][96][288]    =    497664 B   (conv weights repacked, hi)
//   WtL : half [9][96][288]    =    497664 B   (conv weights repacked, lo residual)

#define B_ 2048
#define N_ 256
#define C_ 96
#define H_ 3
#define D_ 32

typedef __half half_t;
typedef __attribute__((ext_vector_type(8))) _Float16 f16x8;
typedef __attribute__((ext_vector_type(4))) float f32x4;

// ---------------- K0: W2p = half(perm(proj_w @ fuse_lh_w)) ; b2 = proj_w @ fuse_b + proj_b
// Column permutation: original k-index j = br*96 + dd*3 + h  ->  j' = br*96 + h*32 + dd,
// so K3 can write attention outputs contiguously per (h,br) block.
__global__ __launch_bounds__(192) void wfdsa_k0(
    const float* __restrict__ proj_w, const float* __restrict__ proj_b,
    const float* __restrict__ fuse_w, const float* __restrict__ fuse_b,
    half_t* __restrict__ W2p, float* __restrict__ b2)
{
  int c = blockIdx.x;      // 96 blocks
  int j = threadIdx.x;     // 192 threads
  float acc = 0.f;
  for (int m = 0; m < 96; ++m)
    acc = fmaf(proj_w[c*96 + m], fuse_w[m*192 + j], acc);
  int br = j / 96, r = j - 96*br, dd = r / 3, h = r - 3*(r/3);
  W2p[c*192 + br*96 + h*32 + dd] = __float2half(acc);
  if (j == 0) {
    float a2 = proj_b[c];
    for (int m = 0; m < 96; ++m) a2 = fmaf(proj_w[c*96 + m], fuse_b[m], a2);
    b2[c] = a2;
  }
}

// ---------------- K0b: repack conv_w [96][288][3][3] f32 -> Wt[t][96][288] half hi/lo
__global__ __launch_bounds__(256) void wfdsa_k0b(
    const float* __restrict__ convw, half_t* __restrict__ WtH, half_t* __restrict__ WtL)
{
  int idx = blockIdx.x*256 + threadIdx.x;       // 9*96*288 = 248832 exactly
  if (idx >= 9*96*288) return;
  int ci = idx % 288; int rest = idx / 288; int co = rest % 96; int t = rest / 96;
  float w = convw[((size_t)co*288 + ci)*9 + t];
  half_t hi = __float2half(w);
  WtH[idx] = hi;
  WtL[idx] = __float2half(w - __half2float(hi));
}

// ---------------- K1: q = x @ q_w^T + q_b, per-head l2 norm -> qn (half)
__global__ __launch_bounds__(256) void wfdsa_k1(
    const float* __restrict__ x, const float* __restrict__ qw,
    const float* __restrict__ qb, half_t* __restrict__ qn)
{
  __shared__ float xs[64*97];   // stride 97: conflict-free per-lane rows
  __shared__ float qs[64*97];
  __shared__ float nrm[192];
  const int tid = threadIdx.x;
  const int b = blockIdx.x;
  const int r0 = blockIdx.y * 64;
  const int lane = tid & 63;
  const int wv = __builtin_amdgcn_readfirstlane(tid >> 6);

  const float* xsrc = x + ((size_t)b*N_ + r0)*C_;
  for (int idx = tid; idx < 64*96; idx += 256)
    xs[(idx/96)*97 + (idx%96)] = xsrc[idx];
  __syncthreads();

  float acc[24];
  #pragma unroll
  for (int u = 0; u < 24; ++u) acc[u] = qb[wv*24 + u];
  for (int i = 0; i < 96; ++i) {
    float xv = xs[lane*97 + i];
    #pragma unroll
    for (int u = 0; u < 24; ++u)
      acc[u] = fmaf(xv, qw[(wv*24 + u)*96 + i], acc[u]);  // uniform -> s_load
  }
  #pragma unroll
  for (int u = 0; u < 24; ++u) qs[lane*97 + wv*24 + u] = acc[u];
  __syncthreads();

  if (tid < 192) {                 // 64 rows x 3 heads
    int r = tid/3, h = tid - 3*(tid/3);
    float ss = 0.f;
    #pragma unroll
    for (int dd = 0; dd < 32; ++dd) {
      float v = qs[r*97 + h*32 + dd];
      ss = fmaf(v, v, ss);
    }
    nrm[tid] = 1.f / fmaxf(sqrtf(ss), 1e-12f);
  }
  __syncthreads();

  for (int idx = tid; idx < 64*96; idx += 256) {
    int r = idx/96, o = idx%96;
    int h = o >> 5, dd = o & 31;
    qn[(((size_t)b*H_ + h)*N_ + r0 + r)*D_ + dd] =
        __float2half(qs[r*97 + o] * nrm[r*3 + h]);
  }
}

// ---------------- K2: per-batch NLWT -> kv_low ; 3x3 conv via f16 MFMA -> kv_high
// One block per batch, 4 waves. LDS 50.8 KB -> 3 blocks/CU.
//   [0, 38480)      highs_T: half [65 rows][296 halves], row stride 592 B (16-aligned).
//                   row = position (64) + zero sentinel row 64; col = sub*96 + c.
//                   After conv: xh_s float[96][65] aliases [0, 24960).
//   [38480, 50768)  A_s: half [96][64]  (approx subband, c-major, for kv_low)
__global__ __launch_bounds__(256, 3) void wfdsa_k2(
    const float* __restrict__ x,
    const float* __restrict__ kvlw, const float* __restrict__ kvlb,
    const float* __restrict__ kvhw, const float* __restrict__ kvhb,
    const half_t* __restrict__ WtH, const half_t* __restrict__ WtL,
    const float* __restrict__ convb,
    half_t* __restrict__ knl, half_t* __restrict__ vtl,
    half_t* __restrict__ knh, half_t* __restrict__ vth)
{
  __shared__ __align__(16) char smem[50768];
  half_t* hT   = (half_t*)smem;               // row r at byte r*592
  float*  xh_s = (float*)smem;                // [96][65] (aliases hT after conv)
  half_t* A_s  = (half_t*)(smem + 38480);     // [96][64]

  const int tid = threadIdx.x;
  const int b = blockIdx.x;
  const int lane = tid & 63;
  const int wv = __builtin_amdgcn_readfirstlane(tid >> 6);
  const int yy = lane >> 3, xx = lane & 7;

  // zero sentinel row 64 of highs_T (conv SAME-padding reads land here)
  if (tid < 148) ((unsigned*)(smem + 64*592))[tid] = 0u;

  // ---- Phase 1: NLWT. Wave-local: rolls via shuffles, NO barriers inside.
  {
    const float* xb = x + (size_t)b*N_*C_;
    const int n00 = yy*32 + xx*2;                       // (2y)*16 + 2x
    const int sl1 = (lane + 8) & 63;                    // (y+1, x)
    const int sl2 = (lane & 56) | ((xx + 1) & 7);       // (y, x+1)
    const int sl3 = (sl1 & 56) | ((xx + 1) & 7);        // (y+1, x+1)
    for (int i = 0; i < 24; i += 2) {
      const int c = wv*24 + i;
      const float2 v00 = *(const float2*)(xb + (size_t)n00*96 + c);
      const float2 v01 = *(const float2*)(xb + (size_t)(n00+1)*96 + c);
      const float2 v10 = *(const float2*)(xb + (size_t)(n00+16)*96 + c);
      const float2 v11 = *(const float2*)(xb + (size_t)(n00+17)*96 + c);
      #pragma unroll
      for (int j = 0; j < 2; ++j) {
        const float x00 = j ? v00.y : v00.x;
        const float x01 = j ? v01.y : v01.x;
        const float x10 = j ? v10.y : v10.x;
        const float x11 = j ? v11.y : v11.x;
        float t0 =  0.8664f*x00 + 0.1026f*x01 + 0.4852f*x10 - 0.0574f*x11;
        float t1 = -0.1026f*x00 + 0.8664f*x01 - 0.0574f*x10 - 0.4852f*x11;
        float t2 =  0.4852f*x00 + 0.0574f*x01 - 0.8664f*x10 + 0.1026f*x11;
        float t3 =  0.0574f*x00 - 0.4852f*x01 - 0.1026f*x10 - 0.8664f*x11;
        float a0 = t0;
        float a1 = __shfl(t1, sl1, 64);
        float a2 = __shfl(t2, sl2, 64);
        float a3 = __shfl(t3, sl3, 64);
        float sA =  1.3968f*a0 + 0.2212f*a1 - 0.2212f*a2 - 1.3968f*a3;
        float sB = -0.2212f*a0 + 1.3968f*a1 - 1.3968f*a2 + 0.2212f*a3;
        float sC = -0.5412f*a0 - 1.3066f*a1 - 1.3066f*a2 - 0.5412f*a3;
        float sD =  1.3066f*a0 - 0.5412f*a1 - 0.5412f*a2 + 1.3066f*a3;
        A_s[(c+j)*64 + lane] = __float2half(sA);
        half_t* hrow = hT + lane*296;         // position-major for MFMA B-frags
        hrow[c+j]        = __float2half(sB);
        hrow[96 + c+j]   = __float2half(sC);
        hrow[192 + c+j]  = __float2half(sD);
      }
    }
  }
  __syncthreads();   // A_s + highs_T visible

  // ---- Phase 2: kv_low (wave = head, lane = position); wave 3 skips ahead to conv
  if (wv < 3) {
    const int h = wv, pos = lane;
    float accK[32], accV[32];
    #pragma unroll
    for (int dd = 0; dd < 32; ++dd) {
      accK[dd] = kvlb[h*32 + dd];
      accV[dd] = kvlb[96 + h*32 + dd];
    }
    for (int c = 0; c < 96; ++c) {
      float av = __half2float(A_s[c*64 + pos]);
      const float* wk  = kvlw + (size_t)(h*32)*96 + c;       // uniform rows -> s_load
      const float* wvp = kvlw + (size_t)(96 + h*32)*96 + c;
      #pragma unroll
      for (int dd = 0; dd < 32; ++dd) {
        accK[dd] = fmaf(av, wk[(size_t)dd*96], accK[dd]);
        accV[dd] = fmaf(av, wvp[(size_t)dd*96], accV[dd]);
      }
    }
    float ss = 0.f;
    #pragma unroll
    for (int dd = 0; dd < 32; ++dd) ss = fmaf(accK[dd], accK[dd], ss);
    float sc = 1.f / fmaxf(sqrtf(ss), 1e-12f);
    half_t* ko = knl + (((size_t)b*H_ + h)*64 + pos)*D_;
    half_t* vo = vtl + ((size_t)b*H_ + h)*D_*64 + pos;
    #pragma unroll
    for (int dd = 0; dd < 32; dd += 2)
      *(__half2*)(ko + dd) = __floats2half2_rn(accK[dd]*sc, accK[dd+1]*sc);
    #pragma unroll
    for (int dd = 0; dd < 32; ++dd) vo[dd*64] = __float2half(accV[dd]);
  }

  // ---- Phase 3: 3x3 SAME conv (288->96) via MFMA f16, hi/lo-split weights.
  f32x4 acc[6];
  {
    #pragma unroll
    for (int m = 0; m < 6; ++m) acc[m] = (f32x4){0.f, 0.f, 0.f, 0.f};
    const int col = lane & 15;          // A row index == B col index
    const int kb  = lane >> 4;          // K-block (8 halves)
    const int pos = wv*16 + col;
    const int py = pos >> 3, px = pos & 7;
    const half_t* ah0 = WtH + (size_t)col*288 + kb*8;
    const half_t* al0 = WtL + (size_t)col*288 + kb*8;
    #pragma unroll 1
    for (int t = 0; t < 9; ++t) {
      const int ny = py + t/3 - 1, nx = px + t%3 - 1;
      const int srow = (((unsigned)ny < 8u) && ((unsigned)nx < 8u)) ? ny*8 + nx : 64;
      const char* bb = smem + srow*592 + kb*16;
      const size_t tb = (size_t)t*96*288;
      for (int kk = 0; kk < 9; ++kk) {
        const f16x8 bf = *(const f16x8*)(bb + kk*64);
        #pragma unroll
        for (int m = 0; m < 6; ++m) {
          const f16x8 ah = *(const f16x8*)(ah0 + tb + (size_t)m*4608 + kk*32);
          const f16x8 al = *(const f16x8*)(al0 + tb + (size_t)m*4608 + kk*32);
          acc[m] = __builtin_amdgcn_mfma_f32_16x16x32_f16(ah, bf, acc[m], 0, 0, 0);
          acc[m] = __builtin_amdgcn_mfma_f32_16x16x32_f16(al, bf, acc[m], 0, 0, 0);
        }
      }
    }
  }
  __syncthreads();   // all conv reads of highs_T done -> region becomes xh_s

  // epilogue: bias + LeakyReLU(0.2) -> xh_s. C/D layout: col=lane&15, row=(lane>>4)*4+reg
  {
    const int col = lane & 15, kb = lane >> 4;
    const int pos = wv*16 + col;
    #pragma unroll
    for (int m = 0; m < 6; ++m) {
      #pragma unroll
      for (int r = 0; r < 4; ++r) {
        const int co = m*16 + kb*4 + r;
        float v = acc[m][r] + convb[co];
        xh_s[co*65 + pos] = (v >= 0.f) ? v : 0.2f*v;
      }
    }
  }
  __syncthreads();

  // ---- Phase 4: kv_high ----
  if (wv < 3) {
    const int h = wv, pos = lane;
    float accK[32], accV[32];
    #pragma unroll
    for (int dd = 0; dd < 32; ++dd) {
      accK[dd] = kvhb[h*32 + dd];
      accV[dd] = kvhb[96 + h*32 + dd];
    }
    for (int c = 0; c < 96; ++c) {
      float av = xh_s[c*65 + pos];
      const float* wk  = kvhw + (size_t)(h*32)*96 + c;
      const float* wvp = kvhw + (size_t)(96 + h*32)*96 + c;
      #pragma unroll
      for (int dd = 0; dd < 32; ++dd) {
        accK[dd] = fmaf(av, wk[(size_t)dd*96], accK[dd]);
        accV[dd] = fmaf(av, wvp[(size_t)dd*96], accV[dd]);
      }
    }
    float ss = 0.f;
    #pragma unroll
    for (int dd = 0; dd < 32; ++dd) ss = fmaf(accK[dd], accK[dd], ss);
    float sc = 1.f / fmaxf(sqrtf(ss), 1e-12f);
    half_t* ko = knh + (((size_t)b*H_ + h)*64 + pos)*D_;
    half_t* vo = vth + ((size_t)b*H_ + h)*D_*64 + pos;
    #pragma unroll
    for (int dd = 0; dd < 32; dd += 2)
      *(__half2*)(ko + dd) = __floats2half2_rn(accK[dd]*sc, accK[dd+1]*sc);
    #pragma unroll
    for (int dd = 0; dd < 32; ++dd) vo[dd*64] = __float2half(accV[dd]);
  }
}

// ---------------- K3: dual-branch MFMA attention + folded fuse/proj MFMA GEMM.
// grid (B, 4), 4 waves x 16 q-rows. Zero __syncthreads: all LDS is wave-private.
//   p_s: per-wave 16x64 half (2 KB), XOR-swizzled (byte ^= (row&7)<<4) for
//        conflict-free b16 writes (C-layout) and b128 A-frag reads.
//   a_s: per-wave 16x200 half, attention outputs at col br*96+h*32+dd (matches W2p).
__global__ __launch_bounds__(256) void wfdsa_k3(
    const half_t* __restrict__ qn,
    const half_t* __restrict__ knl, const half_t* __restrict__ vtl,
    const half_t* __restrict__ knh, const half_t* __restrict__ vth,
    const half_t* __restrict__ W2p, const float* __restrict__ b2,
    const float* __restrict__ lsl, const float* __restrict__ lsh,
    float* __restrict__ out)
{
  __shared__ __align__(16) half_t p_s[4][16*64];
  __shared__ __align__(16) half_t a_s[4][16*200];
  const int tid = threadIdx.x;
  const int b = blockIdx.x;
  const int wv = __builtin_amdgcn_readfirstlane(tid >> 6);
  const int lane = tid & 63;
  const int lo = lane & 15, hi = lane >> 4;
  const int qrow0 = blockIdx.y*64 + wv*16;     // wave's 16 q rows
  char* psc = (char*)&p_s[wv][0];
  half_t* as = &a_s[wv][0];
  const int rsw = (lo & 7) << 4;               // read-side swizzle (row = lo)
  const float LOG100 = 4.605170185988091f;

  for (int h = 0; h < 3; ++h) {
    // Q A-frag: A[row=lo][k=8*hi+j], 16B contiguous
    const f16x8 qa = *(const f16x8*)(qn + (((size_t)b*H_ + h)*N_ + qrow0 + lo)*D_ + hi*8);
    for (int br = 0; br < 2; ++br) {
      const half_t* kn = (br ? knh : knl) + ((size_t)b*H_ + h)*64*D_;
      const half_t* vt = (br ? vth : vtl) + ((size_t)b*H_ + h)*D_*64;
      const float sc = __expf(fminf((br ? lsh : lsl)[h], LOG100));
      // QK^T: S[16q x 64k], B-frag = K[key=nt*16+lo][dd=8*hi+j] straight from global
      f32x4 s[4];
      #pragma unroll
      for (int nt = 0; nt < 4; ++nt) {
        const f16x8 kb = *(const f16x8*)(kn + (nt*16 + lo)*D_ + hi*8);
        s[nt] = __builtin_amdgcn_mfma_f32_16x16x32_f16(qa, kb, (f32x4){0.f,0.f,0.f,0.f}, 0, 0, 0);
      }
      // softmax: lane holds rows 4*hi+rr, keys lo+16*nt. Reduce in-lane + shfl over lo bits.
      float rs[4];
      #pragma unroll
      for (int rr = 0; rr < 4; ++rr) {
        float t0 = s[0][rr]*sc, t1 = s[1][rr]*sc, t2 = s[2][rr]*sc, t3 = s[3][rr]*sc;
        float m = fmaxf(fmaxf(t0, t1), fmaxf(t2, t3));
        m = fmaxf(m, __shfl_xor(m, 1, 64));
        m = fmaxf(m, __shfl_xor(m, 2, 64));
        m = fmaxf(m, __shfl_xor(m, 4, 64));
        m = fmaxf(m, __shfl_xor(m, 8, 64));
        float e0 = __expf(t0 - m), e1 = __expf(t1 - m);
        float e2 = __expf(t2 - m), e3 = __expf(t3 - m);
        float sum = (e0 + e1) + (e2 + e3);
        sum += __shfl_xor(sum, 1, 64);
        sum += __shfl_xor(sum, 2, 64);
        sum += __shfl_xor(sum, 4, 64);
        sum += __shfl_xor(sum, 8, 64);
        rs[rr] = 1.f / sum;                    // folded into O later
        const int row = 4*hi + rr;
        const int rb = row*128;
        const int sw = (row & 7) << 4;
        *(half_t*)(psc + ((rb +  lo*2      ) ^ sw)) = __float2half(e0);
        *(half_t*)(psc + ((rb + (16+lo)*2  ) ^ sw)) = __float2half(e1);
        *(half_t*)(psc + ((rb + (32+lo)*2  ) ^ sw)) = __float2half(e2);
        *(half_t*)(psc + ((rb + (48+lo)*2  ) ^ sw)) = __float2half(e3);
      }
      // PV: A = P (via swizzled LDS transpose), B = vT[dd=nt*16+lo][key=ks*32+8*hi+j]
      const f16x8 pa0 = *(const f16x8*)(psc + ((lo*128      + hi*16) ^ rsw));
      const f16x8 pa1 = *(const f16x8*)(psc + ((lo*128 + 64 + hi*16) ^ rsw));
      const f16x8 vb00 = *(const f16x8*)(vt +  lo*64      + hi*8);
      const f16x8 vb01 = *(const f16x8*)(vt +  lo*64 + 32 + hi*8);
      const f16x8 vb10 = *(const f16x8*)(vt + (16+lo)*64      + hi*8);
      const f16x8 vb11 = *(const f16x8*)(vt + (16+lo)*64 + 32 + hi*8);
      f32x4 o0 = (f32x4){0.f,0.f,0.f,0.f}, o1 = (f32x4){0.f,0.f,0.f,0.f};
      o0 = __builtin_amdgcn_mfma_f32_16x16x32_f16(pa0, vb00, o0, 0, 0, 0);
      o0 = __builtin_amdgcn_mfma_f32_16x16x32_f16(pa1, vb01, o0, 0, 0, 0);
      o1 = __builtin_amdgcn_mfma_f32_16x16x32_f16(pa0, vb10, o1, 0, 0, 0);
      o1 = __builtin_amdgcn_mfma_f32_16x16x32_f16(pa1, vb11, o1, 0, 0, 0);
      // normalize rows, stash into a_s at the W2p-permuted column offset
      const int coff = br*96 + h*32;
      #pragma unroll
      for (int rr = 0; rr < 4; ++rr) {
        const int row = 4*hi + rr;
        as[row*200 + coff +      lo] = __float2half(o0[rr] * rs[rr]);
        as[row*200 + coff + 16 + lo] = __float2half(o1[rr] * rs[rr]);
      }
    }
  }
  // ---- fused out-GEMM: out[16 x 96] = a[16 x 192] @ W2p^T + b2
  f16x8 af[6];
  #pragma unroll
  for (int ks = 0; ks < 6; ++ks)
    af[ks] = *(const f16x8*)(as + lo*200 + ks*32 + hi*8);
  #pragma unroll
  for (int nt = 0; nt < 6; ++nt) {
    f32x4 acc = (f32x4){0.f,0.f,0.f,0.f};
    #pragma unroll
    for (int ks = 0; ks < 6; ++ks) {
      const f16x8 wb = *(const f16x8*)(W2p + (nt*16 + lo)*192 + ks*32 + hi*8);
      acc = __builtin_amdgcn_mfma_f32_16x16x32_f16(af[ks], wb, acc, 0, 0, 0);
    }
    const float bias = b2[nt*16 + lo];
    #pragma unroll
    for (int rr = 0; rr < 4; ++rr)
      out[((size_t)b*N_ + qrow0 + 4*hi + rr)*C_ + nt*16 + lo] = acc[rr] + bias;
  }
}

extern "C" void kernel_launch(void* const* d_in, const int* in_sizes, int n_in,
                              void* d_out, int out_size, void* d_ws, size_t ws_size,
                              hipStream_t stream)
{
  const float* x     = (const float*)d_in[0];
  const float* q_w   = (const float*)d_in[1];
  const float* q_b   = (const float*)d_in[2];
  const float* kvlw  = (const float*)d_in[3];
  const float* kvlb  = (const float*)d_in[4];
  const float* kvhw  = (const float*)d_in[5];
  const float* kvhb  = (const float*)d_in[6];
  const float* convw = (const float*)d_in[7];
  const float* convb = (const float*)d_in[8];
  const float* fusew = (const float*)d_in[9];
  const float* fuseb = (const float*)d_in[10];
  const float* projw = (const float*)d_in[11];
  const float* projb = (const float*)d_in[12];
  const float* lsl   = (const float*)d_in[13];
  const float* lsh   = (const float*)d_in[14];
  float* out = (float*)d_out;

  char* ws = (char*)d_ws;
  half_t* qn  = (half_t*)ws; ws += (size_t)B_*H_*N_*D_*sizeof(half_t);
  half_t* knl = (half_t*)ws; ws += (size_t)B_*H_*64*D_*sizeof(half_t);
  half_t* vtl = (half_t*)ws; ws += (size_t)B_*H_*D_*64*sizeof(half_t);
  half_t* knh = (half_t*)ws; ws += (size_t)B_*H_*64*D_*sizeof(half_t);
  half_t* vth = (half_t*)ws; ws += (size_t)B_*H_*D_*64*sizeof(half_t);
  half_t* W2p = (half_t*)ws; ws += (size_t)96*192*sizeof(half_t);
  float*  b2  = (float*)ws;  ws += (size_t)96*sizeof(float);
  half_t* WtH = (half_t*)ws; ws += (size_t)9*96*288*sizeof(half_t);
  half_t* WtL = (half_t*)ws; ws += (size_t)9*96*288*sizeof(half_t);
  // total used: ~202.4 MB of d_ws

  wfdsa_k0<<<96, 192, 0, stream>>>(projw, projb, fusew, fuseb, W2p, b2);
  wfdsa_k0b<<<972, 256, 0, stream>>>(convw, WtH, WtL);
  wfdsa_k1<<<dim3(B_, 4), 256, 0, stream>>>(x, q_w, q_b, qn);
  wfdsa_k2<<<B_, 256, 0, stream>>>(x, kvlw, kvlb, kvhw, kvhb, WtH, WtL, convb,
                                   knl, vtl, knh, vth);
  wfdsa_k3<<<dim3(B_, 4), 256, 0, stream>>>(qn, knl, vtl, knh, vth, W2p, b2,
                                            lsl, lsh, out);
}